// Round 5
// baseline (80.540 us; speedup 1.0000x reference)
//
#include <hip/hip_runtime.h>
#include <hip/hip_bf16.h>

#define NB 32
#define NN 1024
#define FF 128

typedef __attribute__((ext_vector_type(8))) short short8;
typedef __attribute__((ext_vector_type(4))) float f32x4;

static __device__ __forceinline__ unsigned short f2bf(float x) {
  unsigned int u = __float_as_uint(x);
  u += 0x7fffu + ((u >> 16) & 1u);
  return (unsigned short)(u >> 16);
}

static __device__ __forceinline__ unsigned long long pack4bf(float a, float b, float c, float d) {
  return (unsigned long long)f2bf(a)
       | ((unsigned long long)f2bf(b) << 16)
       | ((unsigned long long)f2bf(c) << 32)
       | ((unsigned long long)f2bf(d) << 48);
}

static __device__ __forceinline__ void gl16(const void* g, void* l) {
  __builtin_amdgcn_global_load_lds((const __attribute__((address_space(1))) void*)g,
                                   (__attribute__((address_space(3))) void*)l, 16, 0, 0);
}

// ---- k1: column sums of A + write bf16 Atilde copy (identity added) ----------
__global__ __launch_bounds__(256) void k1_colsum_cvt(const float* __restrict__ A,
                                                     unsigned short* __restrict__ Ab,
                                                     float* __restrict__ partial) {
  int t = threadIdx.x;          // 0..255 -> columns 4t..4t+3
  int s = blockIdx.x;           // 0..15  -> rows s*64..s*64+63
  int b = blockIdx.y;           // 0..31
  const float* base = A + (size_t)b * NN * NN + (size_t)(s * 64) * NN + (t << 2);
  unsigned short* obase = Ab + (size_t)b * NN * NN + (size_t)(s * 64) * NN + (t << 2);
  int jj = t << 2;
  bool diag_band = ((t >> 4) == s);
  float4 sum = make_float4(0.f, 0.f, 0.f, 0.f);
  #pragma unroll 8
  for (int i = 0; i < 64; ++i) {
    float4 v = *reinterpret_cast<const float4*>(base + (size_t)i * NN);
    if (diag_band) {
      int gi = (s << 6) + i;
      v.x += (gi == jj)     ? 1.f : 0.f;
      v.y += (gi == jj + 1) ? 1.f : 0.f;
      v.z += (gi == jj + 2) ? 1.f : 0.f;
      v.w += (gi == jj + 3) ? 1.f : 0.f;
    }
    sum.x += v.x; sum.y += v.y; sum.z += v.z; sum.w += v.w;
    *reinterpret_cast<unsigned long long*>(obase + (size_t)i * NN) =
        pack4bf(v.x, v.y, v.z, v.w);
  }
  *reinterpret_cast<float4*>(partial + (((b << 4) + s) << 10) + jj) = sum;
}

// ---- k3: HWpT[b][o][j] = bf16( isd[b,j] * sum_k W[k][o]*H[b][j][k] ) ---------
// Self-contained: computes isd_j from partial, converts W^T to bf16 in LDS.
__global__ __launch_bounds__(512) void k3_hw(const float* __restrict__ H,
                                             const float* __restrict__ W,
                                             const float* __restrict__ partial,
                                             unsigned short* __restrict__ HWpT) {
  __shared__ unsigned short Ws[128][136];
  __shared__ unsigned short Hs[128][136];
  __shared__ float isdJ[128];
  int jblk = blockIdx.x;  // 0..7
  int b = blockIdx.y;     // 0..31
  int tid = threadIdx.x, wave = tid >> 6, lane = tid & 63;

  // isd for this block's 128 columns (diag's +1 already in partial)
  if (tid < 128) {
    float d = 0.f;
    #pragma unroll
    for (int s = 0; s < 16; ++s) d += partial[(((b << 4) + s) << 10) + (jblk << 7) + tid];
    isdJ[tid] = rsqrtf(d);
  }
  // Ws[o][k] = bf16(W[k][o])
  #pragma unroll
  for (int p = 0; p < 8; ++p) {
    int idx = (p << 11) + (tid << 2);
    int k = idx >> 7, o = idx & 127;
    const float4 w = *reinterpret_cast<const float4*>(W + idx);
    Ws[o    ][k] = f2bf(w.x);
    Ws[o + 1][k] = f2bf(w.y);
    Ws[o + 2][k] = f2bf(w.z);
    Ws[o + 3][k] = f2bf(w.w);
  }
  // Hs[j_local][k] = bf16(H[b][j][k])
  {
    int r = tid >> 5, c = (tid & 31) << 2;
    const float* Hbase = H + (size_t)b * NN * FF + (size_t)(jblk * 128) * FF;
    #pragma unroll
    for (int p = 0; p < 8; ++p) {
      int row = r + (p << 4);
      const float4 v = *reinterpret_cast<const float4*>(Hbase + (size_t)row * FF + c);
      *reinterpret_cast<unsigned long long*>(&Hs[row][c]) = pack4bf(v.x, v.y, v.z, v.w);
    }
  }
  __syncthreads();

  f32x4 acc[8];
  #pragma unroll
  for (int i = 0; i < 8; ++i) acc[i] = (f32x4){0.f, 0.f, 0.f, 0.f};

  int mrow = (wave << 4) + (lane & 15);
  int koff = (lane >> 4) << 3;
  #pragma unroll
  for (int kk = 0; kk < 4; ++kk) {
    short8 af = *reinterpret_cast<const short8*>(&Ws[mrow][(kk << 5) + koff]);
    #pragma unroll
    for (int nf = 0; nf < 8; ++nf) {
      short8 bf = *reinterpret_cast<const short8*>(&Hs[(nf << 4) + (lane & 15)][(kk << 5) + koff]);
      acc[nf] = __builtin_amdgcn_mfma_f32_16x16x32_bf16(af, bf, acc[nf], 0, 0, 0);
    }
  }

  // D -> Ws (scaled by isd_j), then coalesced 256B-row stores
  int q = lane >> 4, l15 = lane & 15;
  __syncthreads();   // all fragment reads of Ws done before overwrite
  #pragma unroll
  for (int nf = 0; nf < 8; ++nf) {
    int jl = (nf << 4) + l15;
    float sc = isdJ[jl];
    #pragma unroll
    for (int r = 0; r < 4; ++r) {
      Ws[(wave << 4) + (q << 2) + r][jl] = f2bf(acc[nf][r] * sc);
    }
  }
  __syncthreads();
  {
    unsigned short* obase = HWpT + (size_t)b * FF * NN + (size_t)(jblk * 128);
    int c8 = (tid & 15) << 3;
    #pragma unroll
    for (int p = 0; p < 4; ++p) {
      int o = (p << 5) + (tid >> 4);
      *reinterpret_cast<short8*>(obase + (size_t)o * NN + c8) =
          *reinterpret_cast<const short8*>(&Ws[o][c8]);
    }
  }
}

// ---- k4: h = relu(isd_i*(Ab@HWp')[i,f]+bias_f), fused sum-pool ---------------
// 64x128 tile, grid 512 (2 blocks/CU). A: gl16 -> 3 rotating swizzled LDS bufs
// (depth-2); B: register double-buffer. Counted vmcnt, never 0 in-loop.
// No atomics: per-block partial pool -> pooled_part[(b,iblk)][f].
__global__ __launch_bounds__(256) void k4_gcn(const unsigned short* __restrict__ Ab,
                                              const unsigned short* __restrict__ HWpT,
                                              const float* __restrict__ partial,
                                              const float* __restrict__ bias,
                                              float* __restrict__ pooled_part) {
  __shared__ __align__(1024) char ldsA[3 * 8192];   // 24 KB
  __shared__ __align__(16) float ldsIsd[64];
  __shared__ float ldsRed[2][128];
  int fid = blockIdx.x;                  // 0..511
  int nid = (fid & 7) * 64 + (fid >> 3); // XCD-chunked: 4 consecutive b per XCD
  int b = nid >> 4, iblk = nid & 15;
  int i0 = iblk << 6;
  int tid = threadIdx.x, wave = tid >> 6, lane = tid & 63;
  int wm = wave >> 1, wn = wave & 1;
  int l15 = lane & 15, q = lane >> 4;
  int q16 = q << 4;

  // isd for this block's 64 rows (off critical path; visible after first barrier)
  if (tid < 64) {
    float d = 0.f;
    #pragma unroll
    for (int s = 0; s < 16; ++s) d += partial[(((b << 4) + s) << 10) + i0 + tid];
    ldsIsd[tid] = rsqrtf(d);
  }

  // A staging: wave covers rows wave*16..+15, pre-swizzled source chunk
  int r8 = lane >> 3;
  int ch = (lane & 7) ^ r8;
  const unsigned short* aS = Ab + (size_t)b * NN * NN
                           + (size_t)(i0 + (wave << 4) + r8) * NN + (ch << 3);
  // B source: rows f = wn*64 + nf*16 + l15, 16B chunk q
  const unsigned short* bS = HWpT + (size_t)b * FF * NN
                           + (size_t)((wn << 6) + l15) * NN + (q << 3);

  f32x4 acc[2][4];
  #pragma unroll
  for (int m = 0; m < 2; ++m)
    #pragma unroll
    for (int n = 0; n < 4; ++n) acc[m][n] = (f32x4){0.f, 0.f, 0.f, 0.f};

  int swzR = (l15 & 7) << 4;
  int offA[2];
  #pragma unroll
  for (int mr = 0; mr < 2; ++mr)
    offA[mr] = ((wm << 5) + (mr << 4) + l15) * 128 + q16;

  short8 breg[2][4][2];

#define STAGE_A(buf, k0) { \
    const unsigned short* s_ = aS + (k0); \
    char* d_ = ldsA + (buf) * 8192 + (wave << 11); \
    gl16(s_,          d_); \
    gl16(s_ + 8 * NN, d_ + 1024); }

#define LOAD_B(slot, k0) { \
    _Pragma("unroll") \
    for (int nf_ = 0; nf_ < 4; ++nf_) { \
      _Pragma("unroll") \
      for (int kk_ = 0; kk_ < 2; ++kk_) \
        breg[slot][nf_][kk_] = *reinterpret_cast<const short8*>( \
            bS + (size_t)(nf_ << 4) * NN + (k0) + (kk_ << 5)); } }

  // prologue (issue order matches steady state: A then B)
  STAGE_A(0, 0)
  LOAD_B(0, 0)
  STAGE_A(1, 64)

  #pragma unroll
  for (int t = 0; t < 16; ++t) {
    if (t < 15) LOAD_B((t + 1) & 1, (t + 1) * 64)
    if (t < 14) STAGE_A((t + 2) % 3, (t + 2) * 64)
    // steady: leave A(t+1)[2] B(t+1)[8] A(t+2)[2] = 12 in flight
    if (t < 14)       asm volatile("s_waitcnt vmcnt(12)" ::: "memory");
    else if (t == 14) asm volatile("s_waitcnt vmcnt(10)" ::: "memory");
    else              asm volatile("s_waitcnt vmcnt(0)" ::: "memory");
    __builtin_amdgcn_s_barrier();
    const char* Abuf = ldsA + (t % 3) * 8192;
    #pragma unroll
    for (int kk = 0; kk < 2; ++kk) {
      short8 af[2];
      #pragma unroll
      for (int mr = 0; mr < 2; ++mr)
        af[mr] = *reinterpret_cast<const short8*>(Abuf + ((offA[mr] + (kk << 6)) ^ swzR));
      #pragma unroll
      for (int mr = 0; mr < 2; ++mr)
        #pragma unroll
        for (int nf = 0; nf < 4; ++nf)
          acc[mr][nf] = __builtin_amdgcn_mfma_f32_16x16x32_bf16(
              af[mr], breg[t & 1][nf][kk], acc[mr][nf], 0, 0, 0);
    }
    __builtin_amdgcn_s_barrier();
  }
#undef STAGE_A
#undef LOAD_B

  // epilogue: rows i_local = wm*32 + mr*16 + q*4 + r ; cols f = wn*64+nf*16+l15
  #pragma unroll
  for (int nf = 0; nf < 4; ++nf) {
    int f = (wn << 6) + (nf << 4) + l15;
    float bi = bias[f];
    float stot = 0.f;
    #pragma unroll
    for (int mr = 0; mr < 2; ++mr) {
      const f32x4 sc = *reinterpret_cast<const f32x4*>(&ldsIsd[(wm << 5) + (mr << 4) + (q << 2)]);
      stot += fmaxf(acc[mr][nf][0] * sc[0] + bi, 0.f)
            + fmaxf(acc[mr][nf][1] * sc[1] + bi, 0.f)
            + fmaxf(acc[mr][nf][2] * sc[2] + bi, 0.f)
            + fmaxf(acc[mr][nf][3] * sc[3] + bi, 0.f);
    }
    stot += __shfl_xor(stot, 16);
    stot += __shfl_xor(stot, 32);
    if (lane < 16) ldsRed[wm][f] = stot;
  }
  __syncthreads();
  if (tid < 128)
    pooled_part[(((b << 4) + iblk) << 7) + tid] = ldsRed[0][tid] + ldsRed[1][tid];
}

// ---- k5: out[b] = sum_f (sum_slots pooled_part)[f]*fc_w[f] + fc_b ------------
__global__ void k5_out(const float* __restrict__ pp, const float* __restrict__ fcw,
                       const float* __restrict__ fcb, float* __restrict__ out) {
  int b = blockIdx.x, t = threadIdx.x;  // 64 threads
  float s = 0.f;
  #pragma unroll
  for (int slot = 0; slot < 16; ++slot) {
    const float* p = pp + (((b << 4) + slot) << 7);
    s += p[t] * fcw[t] + p[t + 64] * fcw[t + 64];
  }
  #pragma unroll
  for (int off = 1; off < 64; off <<= 1) s += __shfl_xor(s, off);
  if (t == 0) out[b] = s + fcb[0];
}

extern "C" void kernel_launch(void* const* d_in, const int* in_sizes, int n_in,
                              void* d_out, int out_size, void* d_ws, size_t ws_size,
                              hipStream_t stream) {
  const float* A    = (const float*)d_in[0];
  const float* H    = (const float*)d_in[1];
  const float* W    = (const float*)d_in[2];
  const float* bias = (const float*)d_in[3];
  const float* fcw  = (const float*)d_in[4];
  const float* fcb  = (const float*)d_in[5];
  float* out = (float*)d_out;

  float* ws = (float*)d_ws;
  float* partial     = ws;                               // 16*32*1024 f32 (2 MB)
  float* pooled_part = ws + 524288;                      // 32*16*128 f32 (256 KB)
  unsigned short* HWpT = (unsigned short*)(ws + 524288 + 65536);  // 8 MB
  unsigned short* Ab   = HWpT + (size_t)NB * FF * NN;    // 64 MB

  k1_colsum_cvt<<<dim3(16, 32), 256, 0, stream>>>(A, Ab, partial);
  k3_hw        <<<dim3(8, 32), 512, 0, stream>>>(H, W, partial, HWpT);
  k4_gcn       <<<512, 256, 0, stream>>>(Ab, HWpT, partial, bias, pooled_part);
  k5_out       <<<32, 64, 0, stream>>>(pooled_part, fcw, fcb, out);
}

// Round 9
// 66.155 us; speedup vs baseline: 1.2174x; 1.2174x over previous
//
#include <hip/hip_runtime.h>
#include <hip/hip_bf16.h>

#define NB 32
#define NN 1024
#define FF 128

typedef __attribute__((ext_vector_type(8))) short short8;
typedef __attribute__((ext_vector_type(4))) float f32x4;

static __device__ __forceinline__ unsigned short f2bf(float x) {
  unsigned int u = __float_as_uint(x);
  u += 0x7fffu + ((u >> 16) & 1u);
  return (unsigned short)(u >> 16);
}

static __device__ __forceinline__ unsigned long long pack4bf(float a, float b, float c, float d) {
  return (unsigned long long)f2bf(a)
       | ((unsigned long long)f2bf(b) << 16)
       | ((unsigned long long)f2bf(c) << 32)
       | ((unsigned long long)f2bf(d) << 48);
}

static __device__ __forceinline__ void gl16(const void* g, void* l) {
  __builtin_amdgcn_global_load_lds((const __attribute__((address_space(1))) void*)g,
                                   (__attribute__((address_space(3))) void*)l, 16, 0, 0);
}

// ---- k1: column sums of A + write bf16 Atilde copy (identity added) ----------
// [r2-verified, best measured]
__global__ __launch_bounds__(256) void k1_colsum_cvt(const float* __restrict__ A,
                                                     unsigned short* __restrict__ Ab,
                                                     float* __restrict__ partial) {
  int t = threadIdx.x;          // 0..255 -> columns 4t..4t+3
  int s = blockIdx.x;           // 0..15  -> rows s*64..s*64+63
  int b = blockIdx.y;           // 0..31
  const float* base = A + (size_t)b * NN * NN + (size_t)(s * 64) * NN + (t << 2);
  unsigned short* obase = Ab + (size_t)b * NN * NN + (size_t)(s * 64) * NN + (t << 2);
  int jj = t << 2;
  bool diag_band = ((t >> 4) == s);
  float4 sum = make_float4(0.f, 0.f, 0.f, 0.f);
  #pragma unroll 8
  for (int i = 0; i < 64; ++i) {
    float4 v = *reinterpret_cast<const float4*>(base + (size_t)i * NN);
    if (diag_band) {
      int gi = (s << 6) + i;
      v.x += (gi == jj)     ? 1.f : 0.f;
      v.y += (gi == jj + 1) ? 1.f : 0.f;
      v.z += (gi == jj + 2) ? 1.f : 0.f;
      v.w += (gi == jj + 3) ? 1.f : 0.f;
    }
    sum.x += v.x; sum.y += v.y; sum.z += v.z; sum.w += v.w;
    *reinterpret_cast<unsigned long long*>(obase + (size_t)i * NN) =
        pack4bf(v.x, v.y, v.z, v.w);
  }
  *reinterpret_cast<float4*>(partial + (((b << 4) + s) << 10) + jj) = sum;
}

// ---- k3: HWpT[b][o][j] = bf16( isd_j * sum_k W[k][o]*H[b][j][k] ) ------------
// Self-contained (isd_j from partial, W^T bf16 in LDS) [r5-verified body],
// LDS-bounce coalesced stores [r4-verified].
__global__ __launch_bounds__(512) void k3_hw(const float* __restrict__ H,
                                             const float* __restrict__ W,
                                             const float* __restrict__ partial,
                                             unsigned short* __restrict__ HWpT) {
  __shared__ unsigned short Ws[128][136];
  __shared__ unsigned short Hs[128][136];
  __shared__ float isdJ[128];
  int jblk = blockIdx.x;  // 0..7
  int b = blockIdx.y;     // 0..31
  int tid = threadIdx.x, wave = tid >> 6, lane = tid & 63;

  if (tid < 128) {
    float d = 0.f;
    #pragma unroll
    for (int s = 0; s < 16; ++s) d += partial[(((b << 4) + s) << 10) + (jblk << 7) + tid];
    isdJ[tid] = rsqrtf(d);
  }
  // Ws[o][k] = bf16(W[k][o])
  #pragma unroll
  for (int p = 0; p < 8; ++p) {
    int idx = (p << 11) + (tid << 2);
    int k = idx >> 7, o = idx & 127;
    const float4 w = *reinterpret_cast<const float4*>(W + idx);
    Ws[o    ][k] = f2bf(w.x);
    Ws[o + 1][k] = f2bf(w.y);
    Ws[o + 2][k] = f2bf(w.z);
    Ws[o + 3][k] = f2bf(w.w);
  }
  // Hs[jl][k] = bf16(H[b][j][k])
  {
    int r = tid >> 5, c = (tid & 31) << 2;
    const float* Hbase = H + (size_t)b * NN * FF + (size_t)(jblk * 128) * FF;
    #pragma unroll
    for (int p = 0; p < 8; ++p) {
      int row = r + (p << 4);
      const float4 v = *reinterpret_cast<const float4*>(Hbase + (size_t)row * FF + c);
      *reinterpret_cast<unsigned long long*>(&Hs[row][c]) = pack4bf(v.x, v.y, v.z, v.w);
    }
  }
  __syncthreads();

  f32x4 acc[8];
  #pragma unroll
  for (int i = 0; i < 8; ++i) acc[i] = (f32x4){0.f, 0.f, 0.f, 0.f};

  int mrow = (wave << 4) + (lane & 15);
  int koff = (lane >> 4) << 3;
  #pragma unroll
  for (int kk = 0; kk < 4; ++kk) {
    short8 af = *reinterpret_cast<const short8*>(&Ws[mrow][(kk << 5) + koff]);
    #pragma unroll
    for (int nf = 0; nf < 8; ++nf) {
      short8 bf = *reinterpret_cast<const short8*>(&Hs[(nf << 4) + (lane & 15)][(kk << 5) + koff]);
      acc[nf] = __builtin_amdgcn_mfma_f32_16x16x32_bf16(af, bf, acc[nf], 0, 0, 0);
    }
  }

  // D (scaled by isd_j) -> Ws, then coalesced 256B-row stores
  int q = lane >> 4, l15 = lane & 15;
  __syncthreads();   // all Ws fragment reads done before overwrite
  #pragma unroll
  for (int nf = 0; nf < 8; ++nf) {
    int jl = (nf << 4) + l15;
    float sc = isdJ[jl];
    #pragma unroll
    for (int r = 0; r < 4; ++r) {
      Ws[(wave << 4) + (q << 2) + r][jl] = f2bf(acc[nf][r] * sc);
    }
  }
  __syncthreads();
  {
    unsigned short* obase = HWpT + (size_t)b * FF * NN + (size_t)(jblk * 128);
    int c8 = (tid & 15) << 3;
    #pragma unroll
    for (int p = 0; p < 4; ++p) {
      int o = (p << 5) + (tid >> 4);
      *reinterpret_cast<short8*>(obase + (size_t)o * NN + c8) =
          *reinterpret_cast<const short8*>(&Ws[o][c8]);
    }
  }
}

// ---- k4: h = relu(isd_i * (Ab @ HWp')[i,f] + bias_f), fused sum-pool ---------
// r2's exact hot loop (gl16 A+B, XOR-swizzle, 2-barrier). New: XCD-chunked
// block swizzle, self-computed isd_i, atomic-free LDS-reduce epilogue.
__global__ __launch_bounds__(256, 2) void k4_gcn(const unsigned short* __restrict__ Ab,
                                                 const unsigned short* __restrict__ HWpT,
                                                 const float* __restrict__ partial,
                                                 const float* __restrict__ bias,
                                                 float* __restrict__ pooled_part) {
  __shared__ __align__(1024) unsigned short As[64 * 64];    // 8 KB, swizzled
  __shared__ __align__(1024) unsigned short Bs[128 * 64];   // 16 KB, swizzled
  __shared__ __align__(16) float ldsIsd[64];
  __shared__ float ldsRed[4][128];
  int fid = blockIdx.x;                    // 0..511
  int nid = (fid & 7) * 64 + (fid >> 3);   // XCD-chunked: 4 consecutive b/XCD
  int b = nid >> 4, iblk = nid & 15;
  int i0 = iblk << 6;
  int tid = threadIdx.x, wave = tid >> 6, lane = tid & 63;
  int l15 = lane & 15, q = lane >> 4;

  // isd for this block's 64 rows (identity's +1 already in partial)
  if (tid < 64) {
    float d = 0.f;
    #pragma unroll
    for (int s = 0; s < 16; ++s) d += partial[(((b << 4) + s) << 10) + i0 + tid];
    ldsIsd[tid] = rsqrtf(d);
  }

  f32x4 acc[8];
  #pragma unroll
  for (int i = 0; i < 8; ++i) acc[i] = (f32x4){0.f, 0.f, 0.f, 0.f};

  int r8 = lane >> 3;
  int schunk = (lane & 7) ^ r8;
  const unsigned short* aS = Ab + (size_t)b * NN * NN
                           + (size_t)(i0 + (wave << 4) + r8) * NN + (schunk << 3);
  const unsigned short* bS = HWpT + (size_t)b * FF * NN
                           + (size_t)((wave << 5) + r8) * NN + (schunk << 3);
  char* asBase = (char*)As + (wave << 11);
  char* bsBase = (char*)Bs + (wave << 12);
  int mrow = (wave << 4) + l15;
  int q16 = q << 4;
  int aoff0 = (mrow * 128 + q16) ^ ((mrow & 7) << 4);

  for (int k0 = 0; k0 < NN; k0 += 64) {
    gl16(aS + k0,           asBase);
    gl16(aS + k0 + 8 * NN,  asBase + 1024);
    gl16(bS + k0,           bsBase);
    gl16(bS + k0 + 8 * NN,  bsBase + 1024);
    gl16(bS + k0 + 16 * NN, bsBase + 2048);
    gl16(bS + k0 + 24 * NN, bsBase + 3072);
    __syncthreads();
    #pragma unroll
    for (int kk = 0; kk < 2; ++kk) {
      const short8 af = *reinterpret_cast<const short8*>((const char*)As + (aoff0 ^ (kk << 6)));
      #pragma unroll
      for (int nf = 0; nf < 8; ++nf) {
        int br = (nf << 4) + l15;
        const short8 bf = *reinterpret_cast<const short8*>(
            (const char*)Bs + ((br * 128 + (kk << 6) + q16) ^ ((br & 7) << 4)));
        acc[nf] = __builtin_amdgcn_mfma_f32_16x16x32_bf16(af, bf, acc[nf], 0, 0, 0);
      }
    }
    __syncthreads();
  }

  // epilogue: scale rows, +bias, relu, per-wave column sums -> LDS reduce
  const f32x4 sc = *reinterpret_cast<const f32x4*>(&ldsIsd[(wave << 4) + (q << 2)]);
  #pragma unroll
  for (int nf = 0; nf < 8; ++nf) {
    int f = (nf << 4) + l15;
    float bi = bias[f];
    float s = fmaxf(acc[nf][0] * sc[0] + bi, 0.f)
            + fmaxf(acc[nf][1] * sc[1] + bi, 0.f)
            + fmaxf(acc[nf][2] * sc[2] + bi, 0.f)
            + fmaxf(acc[nf][3] * sc[3] + bi, 0.f);
    s += __shfl_xor(s, 16);
    s += __shfl_xor(s, 32);
    if (lane < 16) ldsRed[wave][f] = s;
  }
  __syncthreads();
  if (tid < 128)
    pooled_part[(((b << 4) + iblk) << 7) + tid] =
        ldsRed[0][tid] + ldsRed[1][tid] + ldsRed[2][tid] + ldsRed[3][tid];
}

// ---- k5: out[b] = sum_f (sum_slots pooled_part)[f]*fc_w[f] + fc_b ------------
__global__ void k5_out(const float* __restrict__ pp, const float* __restrict__ fcw,
                       const float* __restrict__ fcb, float* __restrict__ out) {
  int b = blockIdx.x, t = threadIdx.x;  // 64 threads
  float s = 0.f;
  #pragma unroll
  for (int slot = 0; slot < 16; ++slot) {
    const float* p = pp + (((b << 4) + slot) << 7);
    s += p[t] * fcw[t] + p[t + 64] * fcw[t + 64];
  }
  #pragma unroll
  for (int off = 1; off < 64; off <<= 1) s += __shfl_xor(s, off);
  if (t == 0) out[b] = s + fcb[0];
}

extern "C" void kernel_launch(void* const* d_in, const int* in_sizes, int n_in,
                              void* d_out, int out_size, void* d_ws, size_t ws_size,
                              hipStream_t stream) {
  const float* A    = (const float*)d_in[0];
  const float* H    = (const float*)d_in[1];
  const float* W    = (const float*)d_in[2];
  const float* bias = (const float*)d_in[3];
  const float* fcw  = (const float*)d_in[4];
  const float* fcb  = (const float*)d_in[5];
  float* out = (float*)d_out;

  float* ws = (float*)d_ws;
  float* partial     = ws;                               // 16*32*1024 f32 (2 MB)
  float* pooled_part = ws + 524288;                      // 32*16*128 f32 (256 KB)
  unsigned short* HWpT = (unsigned short*)(ws + 524288 + 65536);  // 8 MB
  unsigned short* Ab   = HWpT + (size_t)NB * FF * NN;    // 64 MB

  k1_colsum_cvt<<<dim3(16, 32), 256, 0, stream>>>(A, Ab, partial);
  k3_hw        <<<dim3(8, 32), 512, 0, stream>>>(H, W, partial, HWpT);
  k4_gcn       <<<512, 256, 0, stream>>>(Ab, HWpT, partial, bias, pooled_part);
  k5_out       <<<32, 64, 0, stream>>>(pooled_part, fcw, fcb, out);
}